// Round 8
// baseline (1156.478 us; speedup 1.0000x reference)
//
#include <hip/hip_runtime.h>

#define B_   256
#define NIN_ 512
#define T_   256
#define H1_  512
#define H2_  512
#define OUT_ 128

typedef __attribute__((ext_vector_type(8))) short bf16x8;
typedef __attribute__((ext_vector_type(4))) float f32x4;
typedef __attribute__((address_space(1))) const unsigned int* gl_cu;
typedef __attribute__((address_space(3))) unsigned int* ls_u;

// ---------------------------------------------------------------------------
// init: zero the absmax bit accumulators (ws is poisoned 0xAA).
// ---------------------------------------------------------------------------
__global__ void init_k(unsigned* __restrict__ bits) {
  if (threadIdx.x < 4) bits[threadIdx.x] = 0u;
}

// ---------------------------------------------------------------------------
// Parallel absmax: 64 blocks per tensor, atomicMax on abs-bits (monotone as
// uint for non-negative floats).  Final max identical to a serial fp32 max.
// ---------------------------------------------------------------------------
__global__ void absmax_k(const float* __restrict__ W1, const float* __restrict__ W2,
                         const float* __restrict__ Wr, const float* __restrict__ W3,
                         unsigned* __restrict__ bits) {
  const int tensor = blockIdx.x >> 6;
  const int chunk  = blockIdx.x & 63;
  const float* W; int n4;
  switch (tensor) {
    case 0:  W = W1; n4 = (H1_ * NIN_) >> 2; break;
    case 1:  W = W2; n4 = (H2_ * H1_) >> 2;  break;
    case 2:  W = Wr; n4 = (H2_ * H2_) >> 2;  break;
    default: W = W3; n4 = (OUT_ * H2_) >> 2; break;
  }
  const int tid = threadIdx.x;
  float m = 0.f;
  const float4* W4 = (const float4*)W;
  for (int i = chunk * 256 + tid; i < n4; i += 64 * 256) {
    float4 v = W4[i];
    m = fmaxf(m, fmaxf(fmaxf(fabsf(v.x), fabsf(v.y)), fmaxf(fabsf(v.z), fabsf(v.w))));
  }
  __shared__ float red[256];
  red[tid] = m;
  __syncthreads();
  for (int s = 128; s > 0; s >>= 1) {
    if (tid < s) red[tid] = fmaxf(red[tid], red[tid + s]);
    __syncthreads();
  }
  if (tid == 0) atomicMax(&bits[tensor], __float_as_uint(red[0]));
}

// ---------------------------------------------------------------------------
// Fused quantization (scale = as_float(bits)/127 — identical value to before).
//  blocks 0..1023    : W1 -> fp32 q*s, transposed [NIN][H1]    (W1qT)
//  blocks 1024..2047 : W2 -> bf16 int q, row-major [H2][H1]    (W2bf)
//  blocks 2048..3071 : Wr -> int8 q, presyn-major [H2][H2]     (WrT)
//  blocks 3072..3327 : W3 -> bf16 int q, row-major [OUT][H2]   (W3bf)
// Block 0 also publishes float scales[] for downstream kernels.
// ---------------------------------------------------------------------------
__global__ void quant_all_k(const float* __restrict__ W1, const float* __restrict__ W2,
                            const float* __restrict__ Wr, const float* __restrict__ W3,
                            const unsigned* __restrict__ bits, float* __restrict__ scales,
                            float* __restrict__ W1qT, ushort* __restrict__ W2bf,
                            signed char* __restrict__ WrT, ushort* __restrict__ W3bf) {
  const int blk = blockIdx.x;
  if (blk == 0 && threadIdx.x < 4)
    scales[threadIdx.x] = __uint_as_float(bits[threadIdx.x]) / 127.0f;
  if (blk < 1024) {
    int idx = blk * 256 + threadIdx.x;
    int h = idx & (H1_ - 1), i = idx >> 9;
    float s = __uint_as_float(bits[0]) / 127.0f;
    float q = rintf(W1[h * NIN_ + i] / s);
    q = fminf(fmaxf(q, -127.f), 127.f);
    W1qT[idx] = q * s;
  } else if (blk < 2048) {
    int idx = (blk - 1024) * 256 + threadIdx.x;
    float s = __uint_as_float(bits[1]) / 127.0f;
    float q = rintf(W2[idx] / s);
    q = fminf(fmaxf(q, -127.f), 127.f);
    W2bf[idx] = (ushort)(__float_as_uint(q) >> 16);
  } else if (blk < 3072) {
    int idx = (blk - 2048) * 256 + threadIdx.x;
    int r = idx >> 9, c = idx & (H2_ - 1);
    float s = __uint_as_float(bits[2]) / 127.0f;
    float q = rintf(Wr[idx] / s);
    q = fminf(fmaxf(q, -127.f), 127.f);
    WrT[(size_t)c * H2_ + r] = (signed char)q;
  } else {
    int idx = (blk - 3072) * 256 + threadIdx.x;
    float s = __uint_as_float(bits[3]) / 127.0f;
    float q = rintf(W3[idx] / s);
    q = fminf(fmaxf(q, -127.f), 127.f);
    W3bf[idx] = (ushort)(__float_as_uint(q) >> 16);
  }
}

// ---------------------------------------------------------------------------
// Phase A: cur1[t,b,h] = sum_i data[b,i,t] * W1qT[i,h].  fp32, 128x128 tile,
// BK=32 (16 panels -> half the barrier drains vs BK=16), double-buffered LDS
// with global_load_lds.  FMA order UNCHANGED (ascending k, single accumulator)
// -> bit-identical cur1.  GOLDEN arithmetic.
// ---------------------------------------------------------------------------
__global__ __launch_bounds__(256) void gemm_cur1_k(const float* __restrict__ data,
                                                   const float* __restrict__ W1qT,
                                                   float* __restrict__ cur1) {
  const int b  = blockIdx.y;
  const int t0 = (blockIdx.x >> 2) << 7;
  const int h0 = (blockIdx.x & 3) << 7;
  const int tid = threadIdx.x;

  __shared__ float As[2][32][128];   // 32 KB
  __shared__ float Bs[2][32][128];   // 32 KB  (64 KB total -> 2 blocks/CU)

  const int ty = tid >> 4, tx = tid & 15;
  const int wv = tid >> 6;
  const int ln = tid & 63;
  const int lrow = ln >> 5;
  const int lcol = ln & 31;

  float acc[8][8];
#pragma unroll
  for (int i = 0; i < 8; i++)
#pragma unroll
    for (int j = 0; j < 8; j++) acc[i][j] = 0.f;

  const float* dbase = data + (size_t)b * NIN_ * T_;

  // wave wv stages rows [8*wv, 8*wv+8) of each 32-row panel: 4 wave-loads per
  // matrix (each = 64 lanes x 16B = 2 rows of 512B, wave-uniform LDS base).
  auto issue = [&](int kb, int buf) {
#pragma unroll
    for (int j = 0; j < 4; j++) {
      const int kr = (wv << 3) + (j << 1);
      const float* ga = dbase + (size_t)(kb + kr + lrow) * T_ + t0 + (lcol << 2);
      __builtin_amdgcn_global_load_lds((gl_cu)ga, (ls_u)&As[buf][kr][0], 16, 0, 0);
      const float* gb = W1qT + (size_t)(kb + kr + lrow) * H1_ + h0 + (lcol << 2);
      __builtin_amdgcn_global_load_lds((gl_cu)gb, (ls_u)&Bs[buf][kr][0], 16, 0, 0);
    }
  };

  issue(0, 0);

  for (int p = 0; p < 16; p++) {
    const int cur = p & 1;
    __syncthreads();                 // buf[cur] ready; prev compute done
    if (p < 15) issue((p + 1) << 5, cur ^ 1);
#pragma unroll
    for (int k = 0; k < 32; k++) {
      float4 A0 = *(const float4*)&As[cur][k][ty * 4];
      float4 A1 = *(const float4*)&As[cur][k][64 + ty * 4];
      float4 B0 = *(const float4*)&Bs[cur][k][tx * 4];
      float4 B1 = *(const float4*)&Bs[cur][k][64 + tx * 4];
      float a[8] = {A0.x, A0.y, A0.z, A0.w, A1.x, A1.y, A1.z, A1.w};
      float w[8] = {B0.x, B0.y, B0.z, B0.w, B1.x, B1.y, B1.z, B1.w};
#pragma unroll
      for (int i = 0; i < 8; i++)
#pragma unroll
        for (int j = 0; j < 8; j++)
          acc[i][j] = fmaf(a[i], w[j], acc[i][j]);
    }
  }

#pragma unroll
  for (int i = 0; i < 8; i++) {
    int row = (i < 4) ? (ty * 4 + i) : (64 + ty * 4 + (i - 4));
    float* op = cur1 + (size_t)(t0 + row) * (B_ * H1_) + (size_t)b * H1_ + h0;
    float4 cA = {acc[i][0], acc[i][1], acc[i][2], acc[i][3]};
    float4 cB = {acc[i][4], acc[i][5], acc[i][6], acc[i][7]};
    *(float4*)(op + tx * 4)      = cA;
    *(float4*)(op + 64 + tx * 4) = cB;
  }
}

// ---------------------------------------------------------------------------
// scan1: parallel per-neuron layer-1 LIF scan (op order unchanged).
// ---------------------------------------------------------------------------
__global__ __launch_bounds__(256) void scan1_k(const float* __restrict__ cur1,
                                               unsigned char* __restrict__ s1u,
                                               const float* __restrict__ beta1p,
                                               const float* __restrict__ th1p) {
  const int n = blockIdx.x * 256 + threadIdx.x;
  const float b1 = fminf(fmaxf(beta1p[0], 0.f), 1.f);
  const float th1 = th1p[0];
  const size_t S = (size_t)B_ * H1_;
  float m1 = 0.f;
  for (int t = 0; t < T_; t += 4) {
    float c0 = cur1[(size_t)t * S + n];
    float c1 = cur1[(size_t)(t + 1) * S + n];
    float c2 = cur1[(size_t)(t + 2) * S + n];
    float c3 = cur1[(size_t)(t + 3) * S + n];
    m1 = b1 * m1 + c0; bool s0 = m1 - th1 > 0.f; if (s0) m1 = 0.f;
    s1u[(size_t)t * S + n] = s0;
    m1 = b1 * m1 + c1; bool s1 = m1 - th1 > 0.f; if (s1) m1 = 0.f;
    s1u[(size_t)(t + 1) * S + n] = s1;
    m1 = b1 * m1 + c2; bool s2 = m1 - th1 > 0.f; if (s2) m1 = 0.f;
    s1u[(size_t)(t + 2) * S + n] = s2;
    m1 = b1 * m1 + c3; bool s3 = m1 - th1 > 0.f; if (s3) m1 = 0.f;
    s1u[(size_t)(t + 3) * S + n] = s3;
  }
}

// ---------------------------------------------------------------------------
// Spike GEMM via bf16 MFMA (exact integer sums).  VERIFIED.
// ---------------------------------------------------------------------------
__global__ __launch_bounds__(256) void gemm_spk_k(const unsigned char* __restrict__ A8,
                                                  const ushort* __restrict__ Bw,
                                                  float* __restrict__ C, int N) {
  __shared__ short As[128 * 72];
  __shared__ short Bs[128 * 72];
  const int tid = threadIdx.x;
  const int m0 = blockIdx.y << 7;
  const int n0 = blockIdx.x << 7;
  const int lane = tid & 63, wave = tid >> 6;
  const int quad = lane >> 4, lm = lane & 15;
  const int wm = wave << 5;

  f32x4 acc[2][8];
#pragma unroll
  for (int s = 0; s < 2; s++)
#pragma unroll
    for (int n = 0; n < 8; n++) acc[s][n] = (f32x4){0.f, 0.f, 0.f, 0.f};

  for (int kb = 0; kb < 512; kb += 64) {
    uint4 av[2], bv[4];
#pragma unroll
    for (int i = 0; i < 2; i++) {
      int ch = tid + (i << 8);
      int row = ch >> 2, offB = (ch & 3) << 4;
      av[i] = *(const uint4*)(A8 + (size_t)(m0 + row) * 512 + kb + offB);
    }
#pragma unroll
    for (int i = 0; i < 4; i++) {
      int ch = tid + (i << 8);
      int row = ch >> 3, off = (ch & 7) << 3;
      bv[i] = *(const uint4*)(Bw + (size_t)(n0 + row) * 512 + kb + off);
    }
    __syncthreads();
#pragma unroll
    for (int i = 0; i < 2; i++) {
      int ch = tid + (i << 8);
      int row = ch >> 2, offB = (ch & 3) << 4;
      unsigned u[4] = {av[i].x, av[i].y, av[i].z, av[i].w};
      unsigned d[8];
#pragma unroll
      for (int w = 0; w < 4; w++) {
        unsigned uu = u[w];
        d[2 * w]     = ((uu & 1u) | ((uu & 0x100u) << 8)) * 0x3F80u;
        d[2 * w + 1] = (((uu >> 16) & 1u) | ((uu & 0x1000000u) >> 8)) * 0x3F80u;
      }
      uint4* dst = (uint4*)&As[row * 72 + offB];
      dst[0] = make_uint4(d[0], d[1], d[2], d[3]);
      dst[1] = make_uint4(d[4], d[5], d[6], d[7]);
    }
#pragma unroll
    for (int i = 0; i < 4; i++) {
      int ch = tid + (i << 8);
      int row = ch >> 3, off = (ch & 7) << 3;
      *(uint4*)&Bs[row * 72 + off] = bv[i];
    }
    __syncthreads();
#pragma unroll
    for (int kc = 0; kc < 64; kc += 32) {
      bf16x8 af0 = *(const bf16x8*)&As[(wm + lm) * 72 + kc + quad * 8];
      bf16x8 af1 = *(const bf16x8*)&As[(wm + 16 + lm) * 72 + kc + quad * 8];
      bf16x8 bfr[8];
#pragma unroll
      for (int n = 0; n < 8; n++)
        bfr[n] = *(const bf16x8*)&Bs[((n << 4) + lm) * 72 + kc + quad * 8];
#pragma unroll
      for (int n = 0; n < 8; n++) {
        acc[0][n] = __builtin_amdgcn_mfma_f32_16x16x32_bf16(af0, bfr[n], acc[0][n], 0, 0, 0);
        acc[1][n] = __builtin_amdgcn_mfma_f32_16x16x32_bf16(af1, bfr[n], acc[1][n], 0, 0, 0);
      }
    }
    __syncthreads();
  }

#pragma unroll
  for (int s = 0; s < 2; s++)
#pragma unroll
    for (int n = 0; n < 8; n++) {
      int row = m0 + wm + (s << 4) + quad * 4;
      int col = n0 + (n << 4) + lm;
#pragma unroll
      for (int r = 0; r < 4; r++)
        C[(size_t)(row + r) * N + col] = acc[s][n][r];
    }
}

// ---------------------------------------------------------------------------
// Biased packed accumulate: w bytes are signed weights; w ^ 0x80808080 maps
// each byte to (val+128) EXACTLY.  Even/odd bytes accumulate as packed u16
// (per-thread row count <= 32 -> lane max 8160, no overflow).  Exact integers.
// ---------------------------------------------------------------------------
#define PACC(w) { unsigned x_ = (w) ^ 0x80808080u; aE += x_ & 0x00FF00FFu; aO += (x_ >> 8) & 0x00FF00FFu; }

// ---------------------------------------------------------------------------
// Sequential recurrent layer.  One block per batch row, 1024 threads.
// Round-5 integers EXACTLY (order-independent sums).  Presyn rows 0..255 from
// a 128 KB LDS copy, rows 256..511 from L2.  Packed-u16 biased accumulation.
// ---------------------------------------------------------------------------
__global__ __launch_bounds__(1024) void recurrent_k(
    const float* __restrict__ cur2a,       // [T*B, H2]
    const signed char* __restrict__ WrT,   // [H2][H2] presyn-major
    unsigned char* __restrict__ sru,       // [T*B, H2]
    const float* __restrict__ scales,
    const float* __restrict__ betarp, const float* __restrict__ thrp) {
  const int b = blockIdx.x;
  const int tid = threadIdx.x;
  const float s2sc = scales[1];
  const float srsc = scales[2];
  const float br = fminf(fmaxf(betarp[0], 0.f), 1.f);
  const float thr = thrp[0];

  const unsigned* WrT4 = (const unsigned*)WrT;   // [H2][128] dwords

  __shared__ unsigned WrL[256 * 128];   // 128 KB: presyn rows 0..255
  __shared__ int red[8][H2_];           // 16 KB
  __shared__ int lstLo[2][256];
  __shared__ int lstHi[2][256];
  __shared__ int ncLo[2], ncHi[2];

  {
    const uint4* src = (const uint4*)WrT4;
    uint4* dst = (uint4*)WrL;
    for (int i = tid; i < 8192; i += 1024) dst[i] = src[i];
  }
  if (tid < 2) { ncLo[tid] = 0; ncHi[tid] = 0; }
  __syncthreads();

  float mr = 0.f, sr_own = 0.f;
  const int g = tid >> 7;        // 0..7
  const int c = tid & 127;       // dword column

  for (int t = 0; t < T_; t++) {
    const int old = t & 1, nxt = old ^ 1;
    float c2 = 0.f;
    if (tid < H2_) c2 = cur2a[((size_t)t * B_ + b) * H2_ + tid];
    if (tid == 1022) ncLo[nxt] = 0;
    if (tid == 1023) ncHi[nxt] = 0;
    const int nLo = ncLo[old];
    const int nHi = ncHi[old];
    const int* LLo = lstLo[old];
    const int* LHi = lstHi[old];

    int a4[4] = {0, 0, 0, 0};
    // ---- LDS-resident half (rows < 256) ----
    {
      unsigned aE = 0, aO = 0;
      const int cnt = (nLo > g) ? ((nLo - g + 7) >> 3) : 0;
      int k = g;
      for (; k + 56 < nLo; k += 64) {
        int i0 = LLo[k],      i1 = LLo[k + 8],  i2 = LLo[k + 16], i3 = LLo[k + 24];
        int i4 = LLo[k + 32], i5 = LLo[k + 40], i6 = LLo[k + 48], i7 = LLo[k + 56];
        unsigned w0 = WrL[(i0 << 7) + c], w1 = WrL[(i1 << 7) + c];
        unsigned w2 = WrL[(i2 << 7) + c], w3 = WrL[(i3 << 7) + c];
        unsigned w4 = WrL[(i4 << 7) + c], w5 = WrL[(i5 << 7) + c];
        unsigned w6 = WrL[(i6 << 7) + c], w7 = WrL[(i7 << 7) + c];
        PACC(w0) PACC(w1) PACC(w2) PACC(w3) PACC(w4) PACC(w5) PACC(w6) PACC(w7)
      }
      for (; k < nLo; k += 8) PACC(WrL[(LLo[k] << 7) + c])
      const int bias = cnt << 7;
      a4[0] += (int)(aE & 0xFFFFu) - bias;
      a4[1] += (int)(aO & 0xFFFFu) - bias;
      a4[2] += (int)(aE >> 16) - bias;
      a4[3] += (int)(aO >> 16) - bias;
    }
    // ---- global half (rows >= 256) ----
    {
      unsigned aE = 0, aO = 0;
      const int cnt = (nHi > g) ? ((nHi - g + 7) >> 3) : 0;
      int k = g;
      for (; k + 56 < nHi; k += 64) {
        int i0 = LHi[k],      i1 = LHi[k + 8],  i2 = LHi[k + 16], i3 = LHi[k + 24];
        int i4 = LHi[k + 32], i5 = LHi[k + 40], i6 = LHi[k + 48], i7 = LHi[k + 56];
        unsigned w0 = WrT4[(i0 << 7) + c], w1 = WrT4[(i1 << 7) + c];
        unsigned w2 = WrT4[(i2 << 7) + c], w3 = WrT4[(i3 << 7) + c];
        unsigned w4 = WrT4[(i4 << 7) + c], w5 = WrT4[(i5 << 7) + c];
        unsigned w6 = WrT4[(i6 << 7) + c], w7 = WrT4[(i7 << 7) + c];
        PACC(w0) PACC(w1) PACC(w2) PACC(w3) PACC(w4) PACC(w5) PACC(w6) PACC(w7)
      }
      for (; k < nHi; k += 8) PACC(WrT4[(LHi[k] << 7) + c])
      const int bias = cnt << 7;
      a4[0] += (int)(aE & 0xFFFFu) - bias;
      a4[1] += (int)(aO & 0xFFFFu) - bias;
      a4[2] += (int)(aE >> 16) - bias;
      a4[3] += (int)(aO >> 16) - bias;
    }
    *(int4*)&red[g][c << 2] = make_int4(a4[0], a4[1], a4[2], a4[3]);
    __syncthreads();                               // S1

    bool spike = false;
    if (tid < H2_) {
      int acc = red[0][tid] + red[1][tid] + red[2][tid] + red[3][tid]
              + red[4][tid] + red[5][tid] + red[6][tid] + red[7][tid];
      float h = s2sc * c2 + srsc * (float)acc;
      mr = (br * mr + h) * (1.f - sr_own);
      sr_own = (mr - thr > 0.f) ? 1.f : 0.f;
      sru[((size_t)t * B_ + b) * H2_ + tid] = (unsigned char)(sr_own != 0.f);
      spike = (sr_own != 0.f);
    }
    unsigned long long bm = __ballot(spike);
    if (bm != 0ull) {
      const int lane = tid & 63;
      const int ldr = (int)__ffsll((long long)bm) - 1;
      int* cnt = (tid < 256) ? &ncLo[nxt] : &ncHi[nxt];   // wave-uniform choice
      int* dst = (tid < 256) ? lstLo[nxt] : lstHi[nxt];
      int base = 0;
      if (lane == ldr) base = atomicAdd(cnt, (int)__popcll(bm));
      base = __shfl(base, ldr);
      if (spike)
        dst[base + (int)__popcll(bm & ((1ull << lane) - 1ull))] = tid;
    }
    __syncthreads();                               // S2
  }
}

// ---------------------------------------------------------------------------
// scan3: parallel layer-2 LIF scan over precomputed cur3 sums.
// ---------------------------------------------------------------------------
__global__ __launch_bounds__(256) void scan3_k(const float* __restrict__ cur3,
                                               float* __restrict__ out,
                                               const float* __restrict__ scales,
                                               const float* __restrict__ beta2p,
                                               const float* __restrict__ th2p) {
  const int n = blockIdx.x * 256 + threadIdx.x;
  const float s3sc = scales[3];
  const float b2 = fminf(fmaxf(beta2p[0], 0.f), 1.f);
  const float th2 = th2p[0];
  const size_t S = (size_t)B_ * OUT_;
  float m2 = 0.f;
  for (int t = 0; t < T_; t += 4) {
    float v0 = cur3[(size_t)t * S + n];
    float v1 = cur3[(size_t)(t + 1) * S + n];
    float v2 = cur3[(size_t)(t + 2) * S + n];
    float v3 = cur3[(size_t)(t + 3) * S + n];
    m2 = b2 * m2 + s3sc * v0; float p0 = (m2 - th2 > 0.f) ? 1.f : 0.f; m2 *= (1.f - p0);
    out[(size_t)t * S + n] = p0;
    m2 = b2 * m2 + s3sc * v1; float p1 = (m2 - th2 > 0.f) ? 1.f : 0.f; m2 *= (1.f - p1);
    out[(size_t)(t + 1) * S + n] = p1;
    m2 = b2 * m2 + s3sc * v2; float p2 = (m2 - th2 > 0.f) ? 1.f : 0.f; m2 *= (1.f - p2);
    out[(size_t)(t + 2) * S + n] = p2;
    m2 = b2 * m2 + s3sc * v3; float p3 = (m2 - th2 > 0.f) ? 1.f : 0.f; m2 *= (1.f - p3);
    out[(size_t)(t + 3) * S + n] = p3;
  }
}

// ---------------------------------------------------------------------------
extern "C" void kernel_launch(void* const* d_in, const int* in_sizes, int n_in,
                              void* d_out, int out_size, void* d_ws, size_t ws_size,
                              hipStream_t stream) {
  const float* data  = (const float*)d_in[0];
  const float* W1    = (const float*)d_in[1];
  const float* W2    = (const float*)d_in[2];
  const float* Wr    = (const float*)d_in[3];
  const float* W3    = (const float*)d_in[4];
  const float* beta1 = (const float*)d_in[5];
  const float* th1   = (const float*)d_in[6];
  const float* betar = (const float*)d_in[7];
  const float* thr   = (const float*)d_in[8];
  const float* beta2 = (const float*)d_in[9];
  const float* th2   = (const float*)d_in[10];

  char* ws = (char*)d_ws;
  float*         scales = (float*)ws;                                   // @0 (16B)
  unsigned*      bits   = (unsigned*)(ws + 256);                        // 16B
  float*         W1qT   = (float*)(ws + 4096);                          // 1 MB [NIN][H1]
  ushort*        W2bf   = (ushort*)(ws + 4096 + 1048576);               // 512 KB
  ushort*        W3bf   = (ushort*)(ws + 4096 + 1048576 + 524288);      // 128 KB
  signed char*   WrT    = (signed char*)(ws + 4096 + 1048576 + 524288 + 131072); // 256 KB
  float*         regA   = (float*)(ws + (size_t)4194304);               // 128 MB
  unsigned char* regB   = (unsigned char*)(ws + (size_t)4194304 + 134217728);

  float* cur1  = regA;
  float* cur2a = regA;
  float* cur3  = regA;
  unsigned char* s1u = regB;
  unsigned char* sru = regB + (size_t)33554432;

  hipLaunchKernelGGL(init_k, dim3(1), dim3(64), 0, stream, bits);
  hipLaunchKernelGGL(absmax_k, dim3(256), dim3(256), 0, stream, W1, W2, Wr, W3, bits);
  hipLaunchKernelGGL(quant_all_k, dim3(3328), dim3(256), 0, stream,
                     W1, W2, Wr, W3, bits, scales, W1qT, W2bf, WrT, W3bf);

  hipLaunchKernelGGL(gemm_cur1_k, dim3(8, 256), dim3(256), 0, stream, data, W1qT, cur1);
  hipLaunchKernelGGL(scan1_k, dim3((B_ * H1_) / 256), dim3(256), 0, stream, cur1, s1u, beta1, th1);
  hipLaunchKernelGGL(gemm_spk_k, dim3(4, 512), dim3(256), 0, stream, s1u, W2bf, cur2a, H2_);
  hipLaunchKernelGGL(recurrent_k, dim3(256), dim3(1024), 0, stream, cur2a, WrT, sru, scales, betar, thr);
  hipLaunchKernelGGL(gemm_spk_k, dim3(1, 512), dim3(256), 0, stream, sru, W3bf, cur3, OUT_);
  hipLaunchKernelGGL(scan3_k, dim3((B_ * OUT_) / 256), dim3(256), 0, stream, cur3, (float*)d_out, scales, beta2, th2);
}